// Round 4
// baseline (500.387 us; speedup 1.0000x reference)
//
#include <hip/hip_runtime.h>
#include <stdint.h>

typedef unsigned short u16;
typedef u16   us4 __attribute__((ext_vector_type(4)));
typedef u16   us8 __attribute__((ext_vector_type(8)));
typedef __bf16 bf8 __attribute__((ext_vector_type(8)));
typedef float f4  __attribute__((ext_vector_type(4)));

__device__ __forceinline__ u16 f2bf(float f) {
    uint32_t u = __builtin_bit_cast(uint32_t, f);
    uint32_t r = (u + 0x7fffu + ((u >> 16) & 1u)) >> 16;   // RNE
    return (u16)r;
}
__device__ __forceinline__ float bf2f(u16 s) {
    uint32_t u = ((uint32_t)s) << 16;
    return __builtin_bit_cast(float, u);
}
__device__ __forceinline__ f4 mfma16(bf8 a, bf8 b, f4 c) {
    return __builtin_amdgcn_mfma_f32_16x16x32_bf16(a, b, c, 0, 0, 0);
}
__device__ __forceinline__ u16 max4bf(u16 a, u16 b, u16 c, u16 d) {
    float m = fmaxf(fmaxf(bf2f(a), bf2f(b)), fmaxf(bf2f(c), bf2f(d)));
    return f2bf(m);   // exact: m is already a bf16 value
}

// ---------------------------------------------------------------------------
// Kernel 0a: X transpose+convert.  x[n][c][4096] fp32 -> Xt[n][s][512] bf16.
// ---------------------------------------------------------------------------
__global__ __launch_bounds__(256) void xt_kernel(
    const float* __restrict__ x, u16* __restrict__ Xt)
{
    const int s0 = blockIdx.x * 64, c0 = blockIdx.y * 64, n = blockIdx.z;
    const int tid = threadIdx.x;
    __shared__ u16 lds[64 * 72];   // [s_loc][c_loc], stride 72

    {
        int c_loc = tid & 63, s_seg = (tid >> 6) * 16;
        const float* src = x + ((size_t)n * 512 + c0 + c_loc) * 4096 + s0 + s_seg;
        for (int i4 = 0; i4 < 4; i4++) {
            float4 f = *(const float4*)(src + i4 * 4);
            int s = s_seg + i4 * 4;
            lds[(s + 0) * 72 + c_loc] = f2bf(f.x);
            lds[(s + 1) * 72 + c_loc] = f2bf(f.y);
            lds[(s + 2) * 72 + c_loc] = f2bf(f.z);
            lds[(s + 3) * 72 + c_loc] = f2bf(f.w);
        }
    }
    __syncthreads();
    {
        int s_loc = tid >> 2, c_seg = (tid & 3) * 16;
        u16* dst = Xt + ((size_t)n * 4096 + s0 + s_loc) * 512 + c0 + c_seg;
        *(us8*)(dst)     = *(const us8*)&lds[s_loc * 72 + c_seg];
        *(us8*)(dst + 8) = *(const us8*)&lds[s_loc * 72 + c_seg + 8];
    }
}

// ---------------------------------------------------------------------------
// Kernel 0b: weight convert. Wall_bf[384][512] = [theta;phi;g], Wo_bf[512][256].
// ---------------------------------------------------------------------------
__global__ __launch_bounds__(256) void wconv_kernel(
    const float* __restrict__ w_theta, const float* __restrict__ w_phi,
    const float* __restrict__ w_g, const float* __restrict__ w_o,
    u16* __restrict__ Wall_bf, u16* __restrict__ Wo_bf)
{
    int base = (blockIdx.x * 256 + threadIdx.x) * 4;   // 327680 total elems
    const float* src; u16* dst;
    if (base < 32768)       { src = w_theta + base;          dst = Wall_bf + base; }
    else if (base < 65536)  { src = w_phi + (base - 32768);  dst = Wall_bf + base; }
    else if (base < 196608) { src = w_g + (base - 65536);    dst = Wall_bf + base; }
    else                    { src = w_o + (base - 196608);   dst = Wo_bf + (base - 196608); }
    float4 f = *(const float4*)src;
    us4 v; v[0] = f2bf(f.x); v[1] = f2bf(f.y); v[2] = f2bf(f.z); v[3] = f2bf(f.w);
    *(us4*)dst = v;
}

// ---------------------------------------------------------------------------
// Kernel 1: projection GEMM (transposed output).
// PT[n][s][384] = Xt[n][s][:512] . Wall_bf[row][:512]^T
// ---------------------------------------------------------------------------
__global__ __launch_bounds__(256) void projT_gemm(
    const u16* __restrict__ Xt, const u16* __restrict__ Wall_bf,
    u16* __restrict__ PT)
{
    const int s0 = blockIdx.x * 128;     // 32 tiles
    const int r0 = blockIdx.y * 128;     // 3 tiles (384 rows)
    const int nb = blockIdx.z;
    const int tid = threadIdx.x;
    const int wave = tid >> 6, lane = tid & 63;
    const int quad = lane >> 4, l15 = lane & 15;
    const int wm = (wave >> 1) * 64, wn = (wave & 1) * 64;

    __shared__ u16 a_lds[128 * 40];   // [s_loc][k], stride 40
    __shared__ u16 b_lds[128 * 40];   // [row_loc][k], stride 40

    f4 acc[4][4];
    f4 z = {0.f, 0.f, 0.f, 0.f};
    for (int i = 0; i < 4; i++) for (int j = 0; j < 4; j++) acc[i][j] = z;

    const u16* Abase = Xt + ((size_t)nb * 4096 + s0) * 512;
    const int m = tid >> 1, kseg = (tid & 1) * 16;

    for (int k0 = 0; k0 < 512; k0 += 32) {
        *(us8*)&a_lds[m * 40 + kseg]     = *(const us8*)(Abase + (size_t)m * 512 + k0 + kseg);
        *(us8*)&a_lds[m * 40 + kseg + 8] = *(const us8*)(Abase + (size_t)m * 512 + k0 + kseg + 8);
        *(us8*)&b_lds[m * 40 + kseg]     = *(const us8*)(Wall_bf + (size_t)(r0 + m) * 512 + k0 + kseg);
        *(us8*)&b_lds[m * 40 + kseg + 8] = *(const us8*)(Wall_bf + (size_t)(r0 + m) * 512 + k0 + kseg + 8);
        __syncthreads();
        bf8 af[4], bfr[4];
        for (int i = 0; i < 4; i++)
            af[i]  = __builtin_bit_cast(bf8, *(const us8*)&a_lds[(wm + i*16 + l15)*40 + quad*8]);
        for (int j = 0; j < 4; j++)
            bfr[j] = __builtin_bit_cast(bf8, *(const us8*)&b_lds[(wn + j*16 + l15)*40 + quad*8]);
        for (int i = 0; i < 4; i++)
            for (int j = 0; j < 4; j++)
                acc[i][j] = mfma16(af[i], bfr[j], acc[i][j]);
        __syncthreads();
    }
    for (int i = 0; i < 4; i++) {
        int s_idx = s0 + wm + i * 16 + quad * 4;
        for (int rr = 0; rr < 4; rr++) {
            u16* dst = PT + ((size_t)nb * 4096 + s_idx + rr) * 384 + r0 + wn + l15;
            for (int j = 0; j < 4; j++)
                dst[j * 16] = f2bf(acc[i][j][rr]);
        }
    }
}

// ---------------------------------------------------------------------------
// Kernel 3: phi pool.  PT[n][s][64:128] --2x2 maxpool over s--> phiT[n][t][64]
// ---------------------------------------------------------------------------
__global__ __launch_bounds__(256) void phi_pool2(
    const u16* __restrict__ PT, u16* __restrict__ phiT)
{
    int n = blockIdx.y, t0 = blockIdx.x * 64;
    int tid = threadIdx.x;
    int t_loc = tid >> 2, d0 = (tid & 3) * 16;
    int t = t0 + t_loc;
    int h2 = t >> 5, w2 = t & 31;
    int s00 = h2 * 128 + w2 * 2;
    const u16* base = PT + ((size_t)n * 4096) * 384 + 64 + d0;
    us8 r[4][2];
    int soff[4] = {s00, s00 + 1, s00 + 64, s00 + 65};
    for (int p = 0; p < 4; p++) {
        r[p][0] = *(const us8*)(base + (size_t)soff[p] * 384);
        r[p][1] = *(const us8*)(base + (size_t)soff[p] * 384 + 8);
    }
    us8 o0, o1;
    for (int i = 0; i < 8; i++) {
        o0[i] = max4bf(r[0][0][i], r[1][0][i], r[2][0][i], r[3][0][i]);
        o1[i] = max4bf(r[0][1][i], r[1][1][i], r[2][1][i], r[3][1][i]);
    }
    u16* dst = phiT + ((size_t)n * 1024 + t) * 64 + d0;
    *(us8*)dst = o0;
    *(us8*)(dst + 8) = o1;
}

// ---------------------------------------------------------------------------
// Kernel 4: g pool + transpose. PT[n][s][128:384] --pool--> gP[n][256][1024]
// ---------------------------------------------------------------------------
__global__ __launch_bounds__(256) void g_poolT(
    const u16* __restrict__ PT, u16* __restrict__ gP)
{
    int t0 = blockIdx.x * 64, d0 = blockIdx.y * 64, n = blockIdx.z;
    int tid = threadIdx.x;
    __shared__ u16 lds[64 * 72];   // [d_loc][t_loc], stride 72

    {
        int t_loc = tid & 63, dseg = (tid >> 6) * 16;
        int t = t0 + t_loc;
        int h2 = t >> 5, w2 = t & 31;
        int s00 = h2 * 128 + w2 * 2;
        const u16* base = PT + ((size_t)n * 4096) * 384 + 128 + d0 + dseg;
        us8 r[4][2];
        int soff[4] = {s00, s00 + 1, s00 + 64, s00 + 65};
        for (int p = 0; p < 4; p++) {
            r[p][0] = *(const us8*)(base + (size_t)soff[p] * 384);
            r[p][1] = *(const us8*)(base + (size_t)soff[p] * 384 + 8);
        }
        for (int i = 0; i < 8; i++) {
            lds[(dseg + i) * 72 + t_loc]     = max4bf(r[0][0][i], r[1][0][i], r[2][0][i], r[3][0][i]);
            lds[(dseg + 8 + i) * 72 + t_loc] = max4bf(r[0][1][i], r[1][1][i], r[2][1][i], r[3][1][i]);
        }
    }
    __syncthreads();
    {
        int d_loc = tid >> 2, t_seg = (tid & 3) * 16;
        u16* dst = gP + ((size_t)n * 256 + d0 + d_loc) * 1024 + t0 + t_seg;
        *(us8*)(dst)     = *(const us8*)&lds[d_loc * 72 + t_seg];
        *(us8*)(dst + 8) = *(const us8*)&lds[d_loc * 72 + t_seg + 8];
    }
}

// ---------------------------------------------------------------------------
// Kernel 5: attention, round 4.
//  - 32 q per wave (two 16-q tiles), block = 128 q: the 16 g A-fragment LDS
//    reads per chunk are shared across 2 q-tiles -> LDS read traffic/unit
//    work nearly halves (was the measured floor).
//  - Double-buffered phi/g staging + register prefetch -> ONE barrier/chunk.
//  - p_lds is wave-private (QK write -> PV read within wave, no barrier).
// Grid (32,16) = 512 blocks = exactly 2 blocks/CU. LDS 60 KB.
// ---------------------------------------------------------------------------
__global__ __launch_bounds__(256, 2) void attn_kernel(
    const u16* __restrict__ PT, const u16* __restrict__ phiT,
    const u16* __restrict__ gP, u16* __restrict__ yT)
{
    int n = blockIdx.y;
    int tid = threadIdx.x;
    int wave = tid >> 6, lane = tid & 63, quad = lane >> 4, l15 = lane & 15;
    int q0w = blockIdx.x * 128 + wave * 32;

    __shared__ u16 phi_buf[2][32 * 72];      // [t_loc][d], stride 72
    __shared__ u16 g_buf[2][256 * 40];       // [d2][t_loc], stride 40
    __shared__ u16 p_lds[4][2][16 * 40];     // per-wave, per-qtile [q][t]

    // theta B-fragments for 2 q-tiles (B[n=q][k=d]); strided from PT cols 0:64
    bf8 bth[2][2];
    for (int j = 0; j < 2; j++) {
        const u16* th = PT + ((size_t)n * 4096 + q0w + j * 16 + l15) * 384 + quad * 8;
        bth[j][0] = __builtin_bit_cast(bf8, *(const us8*)(th));
        bth[j][1] = __builtin_bit_cast(bf8, *(const us8*)(th + 32));
    }

    // staging mappings
    const int t_loc = tid >> 3, d0 = (tid & 7) * 8;          // phi: 32x64
    const u16* phi_src = phiT + ((size_t)n * 1024 + t_loc) * 64 + d0;
    const int gr = tid >> 2, gt = (tid & 3) * 8;             // g: 4 rows/thread
    const u16* g_src = gP + ((size_t)n * 256 + gr) * 1024 + gt;

    f4 z = {0.f, 0.f, 0.f, 0.f};
    f4 acc[16][2];
    for (int b = 0; b < 16; b++) { acc[b][0] = z; acc[b][1] = z; }
    float lsum[2] = {0.f, 0.f};

    // prologue: stage chunk 0 into buffer 0
    *(us8*)&phi_buf[0][t_loc * 72 + d0] = *(const us8*)(phi_src);
    for (int p = 0; p < 4; p++)
        *(us8*)&g_buf[0][(p * 64 + gr) * 40 + gt] =
            *(const us8*)(g_src + (size_t)p * 64 * 1024);
    __syncthreads();

    for (int ci = 0; ci < 32; ci++) {
        int cur = ci & 1, nxt = cur ^ 1;
        int nc = (ci + 1 < 32) ? (ci + 1) : ci;
        // prefetch chunk nc into registers
        us8 pf_phi = *(const us8*)(phi_src + (size_t)nc * 2048);
        us8 pf_g[4];
        for (int p = 0; p < 4; p++)
            pf_g[p] = *(const us8*)(g_src + (size_t)p * 64 * 1024 + nc * 32);

        // ---- QK^T (as S^T: D[t][q]) + exp -> p_lds ----
        for (int tt = 0; tt < 32; tt += 16) {
            bf8 ap0 = __builtin_bit_cast(bf8, *(const us8*)&phi_buf[cur][(tt + l15) * 72 + quad * 8]);
            bf8 ap1 = __builtin_bit_cast(bf8, *(const us8*)&phi_buf[cur][(tt + l15) * 72 + 32 + quad * 8]);
            for (int j = 0; j < 2; j++) {
                f4 s = mfma16(ap0, bth[j][0], z);
                s = mfma16(ap1, bth[j][1], s);
                us4 pk;
                float ps = 0.f;
                for (int rr = 0; rr < 4; rr++) {
                    float p = __expf(s[rr]);
                    ps += p;
                    pk[rr] = f2bf(p);
                }
                lsum[j] += ps;
                *(us4*)&p_lds[wave][j][l15 * 40 + tt + quad * 4] = pk;
            }
        }
        // ---- PV: A=G[d2][t], B=P[q][t] -> D[d2][q]; g frags shared over j ----
        bf8 bp0 = __builtin_bit_cast(bf8, *(const us8*)&p_lds[wave][0][l15 * 40 + quad * 8]);
        bf8 bp1 = __builtin_bit_cast(bf8, *(const us8*)&p_lds[wave][1][l15 * 40 + quad * 8]);
        for (int b = 0; b < 16; b++) {
            bf8 ag = __builtin_bit_cast(bf8, *(const us8*)&g_buf[cur][(b * 16 + l15) * 40 + quad * 8]);
            acc[b][0] = mfma16(ag, bp0, acc[b][0]);
            acc[b][1] = mfma16(ag, bp1, acc[b][1]);
        }
        // ---- stage prefetched chunk into the other buffer ----
        *(us8*)&phi_buf[nxt][t_loc * 72 + d0] = pf_phi;
        for (int p = 0; p < 4; p++)
            *(us8*)&g_buf[nxt][(p * 64 + gr) * 40 + gt] = pf_g[p];
        __syncthreads();
    }

    // softmax denominators (per q = l15 of each tile); reduce over 4 quads
    float inv[2];
    for (int j = 0; j < 2; j++) {
        float v = lsum[j];
        v += __shfl_xor(v, 16);
        v += __shfl_xor(v, 32);
        inv[j] = 1.0f / v;
    }
    // epilogue: acc[b][j][rr] = O[d2 = b*16+quad*4+rr][q = qtile j, l15]
    for (int j = 0; j < 2; j++) {
        u16* dst = yT + ((size_t)n * 4096 + q0w + j * 16 + l15) * 256 + quad * 4;
        for (int b = 0; b < 16; b++) {
            us4 o;
            for (int rr = 0; rr < 4; rr++) o[rr] = f2bf(acc[b][j][rr] * inv[j]);
            *(us4*)(dst + b * 16) = o;
        }
    }
}

// ---------------------------------------------------------------------------
// Kernel 6: o-projection + residual, 128x128 tile (projT structure).
// out[n][c][s] = gamma * (Wo_bf[c][:256] . yT[n][s][:256]) + x[n][c][s]
// A = Wo_bf rows (m=c, k-contig), B = yT rows (n=s, k-contig) -> D[c][s].
// ---------------------------------------------------------------------------
__global__ __launch_bounds__(256) void oproj_gemm(
    const u16* __restrict__ Wo_bf, const u16* __restrict__ yT,
    const float* __restrict__ x, const float* __restrict__ gamma,
    float* __restrict__ out)
{
    const int s0 = blockIdx.x * 128;    // 32 tiles
    const int c0 = blockIdx.y * 128;    // 4 tiles
    const int nb = blockIdx.z;
    const int tid = threadIdx.x;
    const int wave = tid >> 6, lane = tid & 63;
    const int quad = lane >> 4, l15 = lane & 15;
    const int wm = (wave >> 1) * 64, wn = (wave & 1) * 64;   // wm: c, wn: s

    __shared__ u16 a_lds[128 * 40];   // [c_loc][k]
    __shared__ u16 b_lds[128 * 40];   // [s_loc][k]

    f4 acc[4][4];
    f4 z = {0.f, 0.f, 0.f, 0.f};
    for (int i = 0; i < 4; i++) for (int j = 0; j < 4; j++) acc[i][j] = z;

    const int m = tid >> 1, kseg = (tid & 1) * 16;
    const u16* Bbase = yT + ((size_t)nb * 4096 + s0) * 256;

    for (int k0 = 0; k0 < 256; k0 += 32) {
        *(us8*)&a_lds[m * 40 + kseg]     = *(const us8*)(Wo_bf + (size_t)(c0 + m) * 256 + k0 + kseg);
        *(us8*)&a_lds[m * 40 + kseg + 8] = *(const us8*)(Wo_bf + (size_t)(c0 + m) * 256 + k0 + kseg + 8);
        *(us8*)&b_lds[m * 40 + kseg]     = *(const us8*)(Bbase + (size_t)m * 256 + k0 + kseg);
        *(us8*)&b_lds[m * 40 + kseg + 8] = *(const us8*)(Bbase + (size_t)m * 256 + k0 + kseg + 8);
        __syncthreads();
        bf8 af[4], bfr[4];
        for (int i = 0; i < 4; i++)
            af[i]  = __builtin_bit_cast(bf8, *(const us8*)&a_lds[(wm + i*16 + l15)*40 + quad*8]);
        for (int j = 0; j < 4; j++)
            bfr[j] = __builtin_bit_cast(bf8, *(const us8*)&b_lds[(wn + j*16 + l15)*40 + quad*8]);
        for (int i = 0; i < 4; i++)
            for (int j = 0; j < 4; j++)
                acc[i][j] = mfma16(af[i], bfr[j], acc[i][j]);
        __syncthreads();
    }
    float g0 = gamma[0];
    for (int i = 0; i < 4; i++) {
        int c = c0 + wm + i * 16 + quad * 4;
        for (int j = 0; j < 4; j++) {
            int s = s0 + wn + j * 16 + l15;
            for (int rr = 0; rr < 4; rr++) {
                size_t idx = ((size_t)nb * 512 + c + rr) * 4096 + s;
                out[idx] = g0 * acc[i][j][rr] + x[idx];
            }
        }
    }
}

// ---------------------------------------------------------------------------
// Workspace layout (bytes). Xt region is dead after projT_gemm, so yT/phiT/gP
// overlay it. Total = 118,095,872 B (~113 MB).
// ---------------------------------------------------------------------------
extern "C" void kernel_launch(void* const* d_in, const int* in_sizes, int n_in,
                              void* d_out, int out_size, void* d_ws, size_t ws_size,
                              hipStream_t stream)
{
    (void)in_sizes; (void)n_in; (void)out_size; (void)ws_size;
    const float* x       = (const float*)d_in[0];
    const float* w_theta = (const float*)d_in[1];
    const float* w_phi   = (const float*)d_in[2];
    const float* w_g     = (const float*)d_in[3];
    const float* w_o     = (const float*)d_in[4];
    const float* gamma   = (const float*)d_in[5];
    float* out = (float*)d_out;

    char* ws = (char*)d_ws;
    u16* Xt      = (u16*)(ws);
    u16* yT      = (u16*)(ws);                 // overlays Xt (dead by then)
    u16* phiT    = (u16*)(ws + 33554432);      // overlays Xt
    u16* gP      = (u16*)(ws + 35651584);      // overlays Xt
    u16* Wall_bf = (u16*)(ws + 67108864);
    u16* Wo_bf   = (u16*)(ws + 67502080);
    u16* PT      = (u16*)(ws + 67764224);

    xt_kernel  <<<dim3(64, 8, 16), 256, 0, stream>>>(x, Xt);
    wconv_kernel<<<320, 256, 0, stream>>>(w_theta, w_phi, w_g, w_o, Wall_bf, Wo_bf);
    projT_gemm <<<dim3(32, 3, 16), 256, 0, stream>>>(Xt, Wall_bf, PT);
    phi_pool2  <<<dim3(16, 16),    256, 0, stream>>>(PT, phiT);
    g_poolT    <<<dim3(16, 4, 16), 256, 0, stream>>>(PT, gP);
    attn_kernel<<<dim3(32, 16),    256, 0, stream>>>(PT, phiT, gP, yT);
    oproj_gemm <<<dim3(32, 4, 16), 256, 0, stream>>>(Wo_bf, yT, x, gamma, out);
}